// Round 4
// baseline (163.993 us; speedup 1.0000x reference)
//
#include <hip/hip_runtime.h>
#include <cstddef>

#define T_STEPS 1024
#define BATCH   32768
#define G1      50
#define H1      32
#define G2      20
#define CT      32      // t-steps per staged chunk

__device__ __forceinline__ float softplus_f(float x) {
    // jax.nn.softplus = max(x,0) + log1p(exp(-|x|))
    float e = __expf(-fabsf(x));
    return fmaxf(x, 0.0f) + __logf(1.0f + e);
}

// One BLOCK (1 wave, 64 lanes) per time step t. Writes a[t] = dt * beta(t).
__global__ __launch_bounds__(64) void beta_kernel(
    const float* __restrict__ t_steps,
    const float* __restrict__ grid1,      // [50]
    const float* __restrict__ spline_w1,  // [50, 32] (g, j)
    const float* __restrict__ base_w1,    // [32]
    const float* __restrict__ grid2,      // [20]
    const float* __restrict__ spline_w2,  // [640]  index j*20+g
    const float* __restrict__ base_w2,    // [32]
    float* __restrict__ a_out)            // [1024] out: dt*beta
{
    __shared__ float se[G1];
    __shared__ float sh[H1];

    const int t    = blockIdx.x;
    const int lane = threadIdx.x;
    const float x  = t_steps[t];

    if (lane < G1) {
        float d = x - grid1[lane];
        se[lane] = __expf(-10.0f * d * d);
    }
    __syncthreads();

    if (lane < H1) {
        float acc = x * base_w1[lane];
        #pragma unroll
        for (int g = 0; g < G1; ++g)
            acc = fmaf(se[g], spline_w1[g * H1 + lane], acc);  // LDS broadcast
        sh[lane] = acc;
    }
    __syncthreads();

    // layer 2: 640 spline terms, 10 per lane; plus base term for lanes < 32
    float acc = 0.0f;
    #pragma unroll
    for (int k = 0; k < 10; ++k) {
        int p = lane + 64 * k;        // 0..639
        int j = p / G2;
        int g = p - j * G2;
        float d = sh[j] - grid2[g];
        acc = fmaf(__expf(-10.0f * d * d), spline_w2[p], acc);
    }
    if (lane < H1) acc = fmaf(sh[lane], base_w2[lane], acc);

    #pragma unroll
    for (int ofs = 32; ofs >= 1; ofs >>= 1)
        acc += __shfl_xor(acc, ofs, 64);

    if (lane == 0) {
        float dt = t_steps[1] - t_steps[0];
        a_out[t] = dt * softplus_f(acc);
    }
}

// One thread per batch element; sequential over T.
// I' = clip(I * (c + a*S)), S' = clip(S * (1 - a*I)); a = dt*beta, c = 1-dt*gamma.
// Compute 32 steps into LDS, then flush with coalesced float4 stores
// (2 KiB per wave-instr — same stream shape as the 6.4 TB/s fill kernel).
__global__ __launch_bounds__(128) void scan_kernel(
    const float* __restrict__ t_steps,
    const float* __restrict__ initial_I,
    const float* __restrict__ gamma_param,
    const float* __restrict__ a_in,   // [1024] dt*beta
    float* __restrict__ out)          // [T, B]
{
    __shared__ float4 sa4[T_STEPS / 4];      // 4 KiB: all a-values
    __shared__ float  sI[CT * 128];          // 16 KiB: staged chunk [t_local][b_local]

    {
        const float4* g4 = (const float4*)a_in;
        #pragma unroll
        for (int i = 0; i < T_STEPS / 4 / 128; ++i)
            sa4[threadIdx.x + i * 128] = g4[threadIdx.x + i * 128];
    }
    __syncthreads();

    const int tid = threadIdx.x;
    const int b0  = blockIdx.x * 128;
    float I = initial_I[b0 + tid];
    float S = 1.0f - I;
    const float gamma = softplus_f(gamma_param[0]);
    const float dt = t_steps[1] - t_steps[0];
    const float c = fmaf(-dt, gamma, 1.0f);   // 1 - dt*gamma

    #pragma unroll 1
    for (int tb = 0; tb < T_STEPS; tb += CT) {
        // ---- compute phase: CT recurrence steps into LDS ----
        float4 q[CT / 4];
        #pragma unroll
        for (int k = 0; k < CT / 4; ++k) q[k] = sa4[tb / 4 + k];
        const float* av = (const float*)q;
        #pragma unroll
        for (int k = 0; k < CT; ++k) {
            float a  = av[k];
            float f  = fmaf(a, S, c);        // c + a*S       (old S)
            float u  = fmaf(-a, I, 1.0f);    // 1 - a*I       (old I)
            float In = I * f;
            float Sn = S * u;
            I = fminf(fmaxf(In, 0.0f), 5.0f);
            S = fminf(fmaxf(Sn, 0.0f), 5.0f);
            sI[k * 128 + tid] = I;           // stride-128: 2-way bank alias = free
        }
        __syncthreads();

        // ---- store phase: 8 coalesced float4 rounds (2 KiB / wave-instr) ----
        const float4* src = (const float4*)sI;
        #pragma unroll
        for (int r = 0; r < (CT * 128) / (128 * 4); ++r) {
            int e  = r * 512 + tid * 4;      // float index within chunk
            int tl = e >> 7;                 // / 128
            int bl = e & 127;
            float4 v = src[e >> 2];
            *(float4*)(out + (size_t)(tb + tl) * BATCH + b0 + bl) = v;
        }
        __syncthreads();
    }
}

extern "C" void kernel_launch(void* const* d_in, const int* in_sizes, int n_in,
                              void* d_out, int out_size, void* d_ws, size_t ws_size,
                              hipStream_t stream) {
    const float* t_steps     = (const float*)d_in[0];
    const float* initial_I   = (const float*)d_in[1];
    const float* grid1       = (const float*)d_in[2];
    const float* spline_w1   = (const float*)d_in[3];
    const float* base_w1     = (const float*)d_in[4];
    const float* grid2       = (const float*)d_in[5];
    const float* spline_w2   = (const float*)d_in[6];
    const float* base_w2     = (const float*)d_in[7];
    const float* gamma_param = (const float*)d_in[8];
    float* out = (float*)d_out;
    float* a_t = (float*)d_ws;   // 1024 floats: dt*beta(t)

    beta_kernel<<<T_STEPS, 64, 0, stream>>>(
        t_steps, grid1, spline_w1, base_w1, grid2, spline_w2, base_w2, a_t);
    scan_kernel<<<BATCH / 128, 128, 0, stream>>>(
        t_steps, initial_I, gamma_param, a_t, out);
}